// Round 8
// baseline (411.634 us; speedup 1.0000x reference)
//
#include <hip/hip_runtime.h>

#define SEQ 512
#define NBAT 512
#define NT 96
#define G 16
#define NBLK (NBAT / G)   // 32 blocks, ONE wave each
#define STRIDE 104        // shorts: 208B row stride = 16B-aligned, 52 dwords -> <=2-way banks

typedef float f32x4 __attribute__((ext_vector_type(4)));
typedef short bf16x8 __attribute__((ext_vector_type(8)));
typedef short s4v __attribute__((ext_vector_type(4)));

static __device__ __forceinline__ short f2bf(float f) {
    unsigned u = __float_as_uint(f);
    u += 0x7FFFu + ((u >> 16) & 1u);       // RNE
    return (short)(u >> 16);
}
static __device__ __forceinline__ float bf2f(short s) {
    return __uint_as_float(((unsigned)(unsigned short)s) << 16);
}

// ONE wave per 16 batches. Wave computes the whole 96x16 step-update:
//   S_i^T = (E^T @ S_{i-1}^T) .* exp(em_i) .* 2^-x   via 6 j-tiles x 3 K-chunks MFMA.
// Zero barriers: same-wave LDS write->read ordered by lgkmcnt (in-order LDS).
// Per-batch power-of-2 rescale: x,K in lanes 0..15, sc broadcast by one shfl.
__launch_bounds__(64, 1)
__global__ void crf_1wave(const float* __restrict__ logits,
                          const int*   __restrict__ tags,
                          const int*   __restrict__ mask,
                          const float* __restrict__ trans,
                          const float* __restrict__ startt,
                          const float* __restrict__ endt,
                          float* __restrict__ out)
{
    const int b0 = blockIdx.x * G;
    const int l = threadIdx.x;     // 0..63
    const int n = l & 15;          // batch column
    const int h = l >> 4;          // row-quad group

    __shared__ short AT[2][G][STRIDE];   // bf16 state, double-buffered
    __shared__ float expend[NT];
    __shared__ unsigned mkb[SEQ];

    for (int i = l; i < SEQ; i += 64) {
        unsigned v = 0;
        for (int g = 0; g < G; ++g)
            v |= (mask[(size_t)(b0 + g) * SEQ + i] != 0 ? 1u : 0u) << g;
        mkb[i] = v;
    }
    for (int j = l; j < NT; j += 64) expend[j] = __expf(endt[j]);

    // E^T MFMA A-fragments: ea[T][s][e] = bf16(exp(T[32s+8h+e][16T+n]))
    bf16x8 ea[6][3];
#pragma unroll
    for (int T = 0; T < 6; ++T)
#pragma unroll
        for (int s = 0; s < 3; ++s)
#pragma unroll
            for (int e = 0; e < 8; ++e)
                ea[T][s][e] = f2bf(__expf(trans[(32 * s + 8 * h + e) * NT + 16 * T + n]));

    const float* emg = logits + (size_t)(b0 + n) * SEQ * NT;

    // init state: lane (n,h) owns j = 16T+4h+{0..3} of batch-column n
    s4v prev[6];
#pragma unroll
    for (int T = 0; T < 6; ++T) {
        s4v p;
#pragma unroll
        for (int r = 0; r < 4; ++r) {
            const int j = 16 * T + 4 * h + r;
            p[r] = f2bf(__expf(startt[j] + emg[j]));
        }
        prev[T] = p;
        *(s4v*)&AT[0][n][16 * T + 4 * h] = p;
    }

    int K = 0;
    int x = ((int)((__float_as_uint(bf2f(prev[0][0])) >> 23) & 0xFFu)) - 127; // valid in lanes 0-15
    float sc = __shfl(__uint_as_float((unsigned)(127 - x) << 23), n);

    // emission prefetch, depth 3
    float4 emq0[6], emq1[6], emq2[6];
#pragma unroll
    for (int T = 0; T < 6; ++T) {
        emq0[T] = *(const float4*)&emg[1 * NT + 16 * T + 4 * h];
        emq1[T] = *(const float4*)&emg[2 * NT + 16 * T + 4 * h];
        emq2[T] = *(const float4*)&emg[3 * NT + 16 * T + 4 * h];
    }
    __syncthreads();   // once (covers setup LDS); loop itself is barrier-free

    for (int i = 1; i < SEQ; ++i) {
        const int rb = (i - 1) & 1, wb = i & 1;

        // issue prefetch of row i+3 first (stays in flight ~3 steps)
        const int ip = (i + 3 < SEQ) ? i + 3 : SEQ - 1;
        float4 emn[6];
#pragma unroll
        for (int T = 0; T < 6; ++T)
            emn[T] = *(const float4*)&emg[ip * NT + 16 * T + 4 * h];

        const unsigned mk = (mkb[i] >> n) & 1u;

        // B fragments: column n, k = 32s + 8h + e
        bf16x8 Bf0 = *(const bf16x8*)&AT[rb][n][ 0 + 8 * h];
        bf16x8 Bf1 = *(const bf16x8*)&AT[rb][n][32 + 8 * h];
        bf16x8 Bf2 = *(const bf16x8*)&AT[rb][n][64 + 8 * h];

        // w = exp(em_i) * sc  (off the MFMA dependency path)
        float ws[6][4];
#pragma unroll
        for (int T = 0; T < 6; ++T) {
            ws[T][0] = __expf(emq0[T].x) * sc;
            ws[T][1] = __expf(emq0[T].y) * sc;
            ws[T][2] = __expf(emq0[T].z) * sc;
            ws[T][3] = __expf(emq0[T].w) * sc;
        }

#pragma unroll
        for (int T = 0; T < 6; ++T) {
            f32x4 acc = {0.f, 0.f, 0.f, 0.f};
            acc = __builtin_amdgcn_mfma_f32_16x16x32_bf16(ea[T][0], Bf0, acc, 0, 0, 0);
            acc = __builtin_amdgcn_mfma_f32_16x16x32_bf16(ea[T][1], Bf1, acc, 0, 0, 0);
            acc = __builtin_amdgcn_mfma_f32_16x16x32_bf16(ea[T][2], Bf2, acc, 0, 0, 0);
            s4v nw;
            nw[0] = f2bf(acc[0] * ws[T][0]);
            nw[1] = f2bf(acc[1] * ws[T][1]);
            nw[2] = f2bf(acc[2] * ws[T][2]);
            nw[3] = f2bf(acc[3] * ws[T][3]);
            if (mk) prev[T] = nw;                       // per-lane cndmask
            *(s4v*)&AT[wb][n][16 * T + 4 * h] = prev[T];
        }

        // scale ledger (lag-1): stored = true * 2^-K
        if (mk) K += x;
        x = ((int)((__float_as_uint(bf2f(prev[0][0])) >> 23) & 0xFFu)) - 127;
        sc = __shfl(__uint_as_float((unsigned)(127 - x) << 23), n);

#pragma unroll
        for (int T = 0; T < 6; ++T) { emq0[T] = emq1[T]; emq1[T] = emq2[T]; emq2[T] = emn[T]; }
    }
    __syncthreads();

    // ---- numerator partials: lane (n,h) takes steps i = h, h+4, ... ----
    const int* tgp = tags + (size_t)(b0 + n) * SEQ;
    float pn = 0.f;
    int cnt = 0;
    for (int i = h; i < SEQ; i += 4) {
        const unsigned mki = (mkb[i] >> n) & 1u;
        cnt += (int)mki;
        if (i >= 1 && mki) {
            const int tp = tgp[i - 1], tc = tgp[i];
            pn += trans[tp * NT + tc] + emg[i * NT + tc];
        }
    }
    pn  += __shfl_xor(pn, 16);  pn  += __shfl_xor(pn, 32);
    cnt += __shfl_xor(cnt, 16); cnt += __shfl_xor(cnt, 32);

    if (l < G) {   // lane n finalizes batch b0+n
        const int tg0 = tgp[0];
        const int tgl = tgp[cnt - 1];
        const float num = startt[tg0] + emg[tg0] + endt[tgl] + pn;

        float sd = 0.f;
        const int fb = (SEQ - 1) & 1;
        for (int j = 0; j < NT; ++j)
            sd += bf2f(AT[fb][n][j]) * expend[j];
        float llh = num - (__logf(sd) + (float)K * 0.69314718055994531f);

        llh += __shfl_xor(llh, 1);
        llh += __shfl_xor(llh, 2);
        llh += __shfl_xor(llh, 4);
        llh += __shfl_xor(llh, 8);
        if (l == 0) atomicAdd(out, llh);
    }
}

extern "C" void kernel_launch(void* const* d_in, const int* in_sizes, int n_in,
                              void* d_out, int out_size, void* d_ws, size_t ws_size,
                              hipStream_t stream)
{
    const float* logits = (const float*)d_in[0];
    const int*   tags   = (const int*)  d_in[1];
    const int*   mask   = (const int*)  d_in[2];
    const float* trans  = (const float*)d_in[3];
    const float* startt = (const float*)d_in[4];
    const float* endt   = (const float*)d_in[5];
    float* out = (float*)d_out;

    hipMemsetAsync(out, 0, out_size * sizeof(float), stream);
    crf_1wave<<<NBLK, 64, 0, stream>>>(logits, tags, mask, trans,
                                       startt, endt, out);
}

// Round 9
// 257.317 us; speedup vs baseline: 1.5997x; 1.5997x over previous
//
#include <hip/hip_runtime.h>

#define SEQ 512
#define NBAT 512
#define NT 96
#define G 16
#define NBLK (NBAT / G)   // 32 blocks
#define TPB 192           // 3 waves; wave w owns j-tiles {2w, 2w+1}
#define STRIDE 104        // shorts; 208B = 13 x 16B -> conflict-free b128

typedef float f32x4 __attribute__((ext_vector_type(4)));
typedef short bf16x8 __attribute__((ext_vector_type(8)));
typedef short s4v __attribute__((ext_vector_type(4)));

static __device__ __forceinline__ short f2bf(float f) {
    unsigned u = __float_as_uint(f);
    u += 0x7FFFu + ((u >> 16) & 1u);       // RNE
    return (short)(u >> 16);
}
static __device__ __forceinline__ float bf2f(short s) {
    return __uint_as_float(((unsigned)(unsigned short)s) << 16);
}

// 16 batches/block, 3 waves. Per step: S_i^T = (E^T @ S_{i-1}^T) .* exp(em_i) .* 2^-x
// via 6 MFMA tiles (2 per wave, 3 chained K-chunks each). State bf16 in LDS,
// double-buffered, ONE lgkm-only barrier/step. Scale sc = 2^-x derived lag-0
// from the state fragment itself via one __shfl (no scl LDS round-trip);
// integer exponent ledger K kept in lanes 0..15 of every wave (identical).
__launch_bounds__(TPB, 1)
__global__ void crf_w3(const float* __restrict__ logits,
                       const int*   __restrict__ tags,
                       const int*   __restrict__ mask,
                       const float* __restrict__ trans,
                       const float* __restrict__ startt,
                       const float* __restrict__ endt,
                       float* __restrict__ out)
{
    const int b0 = blockIdx.x * G;
    const int t = threadIdx.x;
    const int w = t >> 6;          // wave 0..2
    const int l = t & 63;
    const int n = l & 15;          // batch column
    const int h = l >> 4;          // quad 0..3
    const int T0 = 2 * w, T1 = 2 * w + 1;

    __shared__ short AT[2][G][STRIDE];   // bf16 state, double-buffered
    __shared__ unsigned mkb[SEQ];
    __shared__ float expend[NT];
    __shared__ float nred[12][G];
    __shared__ int   cred[12][G];

    for (int i = t; i < SEQ; i += TPB) {
        unsigned v = 0;
        for (int g = 0; g < G; ++g)
            v |= (mask[(size_t)(b0 + g) * SEQ + i] != 0 ? 1u : 0u) << g;
        mkb[i] = v;
    }
    if (t < NT) expend[t] = __expf(endt[t]);

    // E^T MFMA A-fragments for my two tiles (row = n-slot of layout, k = 32s+8h+e)
    bf16x8 ea0[3], ea1[3];
#pragma unroll
    for (int s = 0; s < 3; ++s)
#pragma unroll
        for (int e = 0; e < 8; ++e) {
            ea0[s][e] = f2bf(__expf(trans[(32 * s + 8 * h + e) * NT + 16 * T0 + n]));
            ea1[s][e] = f2bf(__expf(trans[(32 * s + 8 * h + e) * NT + 16 * T1 + n]));
        }

    const float* emg = logits + (size_t)(b0 + n) * SEQ * NT;

    // init state: lane (n,h) of wave w owns j = 16T+4h+{0..3}, T in {T0,T1}
    s4v prev0, prev1;
#pragma unroll
    for (int r = 0; r < 4; ++r) {
        const int j0 = 16 * T0 + 4 * h + r;
        const int j1 = 16 * T1 + 4 * h + r;
        prev0[r] = f2bf(__expf(startt[j0] + emg[j0]));
        prev1[r] = f2bf(__expf(startt[j1] + emg[j1]));
    }
    *(s4v*)&AT[0][n][16 * T0 + 4 * h] = prev0;
    *(s4v*)&AT[0][n][16 * T1 + 4 * h] = prev1;

    int K = 0;

    // emission prefetch, depth 3, for my two j-slices
    float4 eq0a = *(const float4*)&emg[1 * NT + 16 * T0 + 4 * h];
    float4 eq0b = *(const float4*)&emg[1 * NT + 16 * T1 + 4 * h];
    float4 eq1a = *(const float4*)&emg[2 * NT + 16 * T0 + 4 * h];
    float4 eq1b = *(const float4*)&emg[2 * NT + 16 * T1 + 4 * h];
    float4 eq2a = *(const float4*)&emg[3 * NT + 16 * T0 + 4 * h];
    float4 eq2b = *(const float4*)&emg[3 * NT + 16 * T1 + 4 * h];
    __syncthreads();

    for (int i = 1; i < SEQ; ++i) {
        const int rb = (i - 1) & 1, wb = i & 1;

        // B fragments (identical across waves): col n, k = 32s + 8h + e
        const bf16x8 Bf0 = *(const bf16x8*)&AT[rb][n][ 0 + 8 * h];
        const bf16x8 Bf1 = *(const bf16x8*)&AT[rb][n][32 + 8 * h];
        const bf16x8 Bf2 = *(const bf16x8*)&AT[rb][n][64 + 8 * h];

        // prefetch em row i+3 (stays in flight across barriers)
        const int ip = (i + 3 < SEQ) ? i + 3 : SEQ - 1;
        const float4 ena = *(const float4*)&emg[ip * NT + 16 * T0 + 4 * h];
        const float4 enb = *(const float4*)&emg[ip * NT + 16 * T1 + 4 * h];

        const unsigned mk = (mkb[i] >> n) & 1u;

        // w = exp(em_i): independent of the LDS reads -> hides their latency
        const float w0 = __expf(eq0a.x), w1 = __expf(eq0a.y);
        const float w2 = __expf(eq0a.z), w3 = __expf(eq0a.w);
        const float w4 = __expf(eq0b.x), w5 = __expf(eq0b.y);
        const float w6 = __expf(eq0b.z), w7 = __expf(eq0b.w);

        // sc = 2^-x, x = exponent of A_prev[0] of batch n (lane n quad0 holds it)
        const float refA0 = __shfl(bf2f(Bf0[0]), n);
        const int x = (int)((__float_as_uint(refA0) >> 23) & 0xFFu) - 127;
        const float sc = __uint_as_float((unsigned)(127 - x) << 23);

        f32x4 acc0 = {0.f, 0.f, 0.f, 0.f};
        f32x4 acc1 = {0.f, 0.f, 0.f, 0.f};
        acc0 = __builtin_amdgcn_mfma_f32_16x16x32_bf16(ea0[0], Bf0, acc0, 0, 0, 0);
        acc1 = __builtin_amdgcn_mfma_f32_16x16x32_bf16(ea1[0], Bf0, acc1, 0, 0, 0);
        acc0 = __builtin_amdgcn_mfma_f32_16x16x32_bf16(ea0[1], Bf1, acc0, 0, 0, 0);
        acc1 = __builtin_amdgcn_mfma_f32_16x16x32_bf16(ea1[1], Bf1, acc1, 0, 0, 0);
        acc0 = __builtin_amdgcn_mfma_f32_16x16x32_bf16(ea0[2], Bf2, acc0, 0, 0, 0);
        acc1 = __builtin_amdgcn_mfma_f32_16x16x32_bf16(ea1[2], Bf2, acc1, 0, 0, 0);

        s4v nw0, nw1;
        nw0[0] = f2bf(acc0[0] * (w0 * sc));
        nw0[1] = f2bf(acc0[1] * (w1 * sc));
        nw0[2] = f2bf(acc0[2] * (w2 * sc));
        nw0[3] = f2bf(acc0[3] * (w3 * sc));
        nw1[0] = f2bf(acc1[0] * (w4 * sc));
        nw1[1] = f2bf(acc1[1] * (w5 * sc));
        nw1[2] = f2bf(acc1[2] * (w6 * sc));
        nw1[3] = f2bf(acc1[3] * (w7 * sc));
        if (mk) { prev0 = nw0; prev1 = nw1; K += x; }
        *(s4v*)&AT[wb][n][16 * T0 + 4 * h] = prev0;
        *(s4v*)&AT[wb][n][16 * T1 + 4 * h] = prev1;

        eq0a = eq1a; eq0b = eq1b;
        eq1a = eq2a; eq1b = eq2b;
        eq2a = ena;  eq2b = enb;

        // lgkm-only barrier: state visible, em prefetches stay in flight
        asm volatile("s_waitcnt lgkmcnt(0)\n\ts_barrier" ::: "memory");
    }
    __syncthreads();

    // ---- numerator partials: chunk c = t>>4 (0..11), batch gn = t&15 ----
    const int c = t >> 4;
    const int gn = t & 15;
    const float* emp = logits + (size_t)(b0 + gn) * SEQ * NT;
    const int* tgp = tags + (size_t)(b0 + gn) * SEQ;
    float pn = 0.f;
    int pc = 0;
    for (int i = 1 + c; i < SEQ; i += 12) {
        if ((mkb[i] >> gn) & 1u) {
            const int tp = tgp[i - 1], tc = tgp[i];
            pn += trans[tp * NT + tc] + emp[i * NT + tc];
        }
    }
    for (int i = c; i < SEQ; i += 12) pc += (int)((mkb[i] >> gn) & 1u);
    nred[c][gn] = pn; cred[c][gn] = pc;
    __syncthreads();

    if (t < G) {   // lane t finalizes batch b0+t (its K ledger matches: n==t)
        float num = 0.f; int cnt = 0;
        for (int cc = 0; cc < 12; ++cc) { num += nred[cc][t]; cnt += cred[cc][t]; }
        const int* tgq = tags + (size_t)(b0 + t) * SEQ;
        const int tg0 = tgq[0];
        const int tgl = tgq[cnt - 1];
        num += startt[tg0] + logits[(size_t)(b0 + t) * SEQ * NT + tg0] + endt[tgl];

        float sd = 0.f;
        const int fb = (SEQ - 1) & 1;
        for (int j = 0; j < NT; ++j)
            sd += bf2f(AT[fb][t][j]) * expend[j];
        float llh = num - (__logf(sd) + (float)K * 0.69314718055994531f);

        llh += __shfl_xor(llh, 1);
        llh += __shfl_xor(llh, 2);
        llh += __shfl_xor(llh, 4);
        llh += __shfl_xor(llh, 8);
        if (t == 0) atomicAdd(out, llh);
    }
}

extern "C" void kernel_launch(void* const* d_in, const int* in_sizes, int n_in,
                              void* d_out, int out_size, void* d_ws, size_t ws_size,
                              hipStream_t stream)
{
    const float* logits = (const float*)d_in[0];
    const int*   tags   = (const int*)  d_in[1];
    const int*   mask   = (const int*)  d_in[2];
    const float* trans  = (const float*)d_in[3];
    const float* startt = (const float*)d_in[4];
    const float* endt   = (const float*)d_in[5];
    float* out = (float*)d_out;

    hipMemsetAsync(out, 0, out_size * sizeof(float), stream);
    crf_w3<<<NBLK, TPB, 0, stream>>>(logits, tags, mask, trans,
                                     startt, endt, out);
}

// Round 11
// 59.267 us; speedup vs baseline: 6.9454x; 4.3417x over previous
//
#include <hip/hip_runtime.h>

#define SEQ 512
#define NBAT 512
#define NT 96
#define G 16
#define P 16
#define SEGL (SEQ / P)        // 32 steps per segment
#define OV 16                 // warm-up overlap (contraction ~10x/step)
#define TPB 384               // 6 waves; wave w owns j-tile [16w, 16w+16)
#define STRIDE 104            // shorts; 208B row = 13 x 16B -> <=2-way banks
#define LN2 0.69314718055994531f

typedef float f32x4 __attribute__((ext_vector_type(4)));
typedef short bf16x8 __attribute__((ext_vector_type(8)));
typedef short s4v __attribute__((ext_vector_type(4)));

static __device__ __forceinline__ short f2bf(float f) {
    unsigned u = __float_as_uint(f);
    u += 0x7FFFu + ((u >> 16) & 1u);       // RNE
    return (short)(u >> 16);
}
static __device__ __forceinline__ float bf2f(short s) {
    return __uint_as_float(((unsigned)(unsigned short)s) << 16);
}

// Segmented CRF forward. Block (sid, grp): segment sid of batches [16grp,16grp+16).
// Chains sid>0 start from ones OV steps early; Birkhoff contraction makes the
// direction exact at the segment entry; the unknown per-segment scalar
// telescopes through interface snapshots Lin/Lout (log(sum state) + K*ln2,
// exact pow2 ledger). Steps run only over i in [1, SEQ-1].
__launch_bounds__(TPB, 1)
__global__ void crf_seg(const float* __restrict__ logits,
                        const int*   __restrict__ tags,
                        const int*   __restrict__ mask,
                        const float* __restrict__ trans,
                        const float* __restrict__ startt,
                        const float* __restrict__ endt,
                        float* __restrict__ wsLin, float* __restrict__ wsLout,
                        float* __restrict__ wsNum, float* __restrict__ wsLend)
{
    const int sid = blockIdx.x & (P - 1);
    const int grp = blockIdx.x >> 4;
    const int b0 = grp * G;
    const int t = threadIdx.x;
    const int w = t >> 6;          // wave -> j-tile
    const int l = t & 63;
    const int g = l & 15;          // batch column
    const int q = l >> 4;          // quad

    const int i0 = (sid == 0) ? 0 : sid * SEGL - OV;  // state position before 1st step
    const int qs = sid * SEGL;                        // Lin snapshot position
    const int i1 = (sid == P - 1) ? SEQ - 1 : (sid + 1) * SEGL;  // last step (incl.)

    __shared__ short AT[2][G][STRIDE];
    __shared__ float sclf[2][G];
    __shared__ unsigned mkb[SEGL + OV + 1];
    __shared__ float nred[24][G];
    __shared__ int   cred[24][G];
    __shared__ float expend_s[NT];

    // mask window bits: mkb[d] bit g = mask[b0+g][i0+d], d in [0, i1-i0]
    for (int d = t; d <= i1 - i0; d += TPB) {
        unsigned v = 0;
        const int i = i0 + d;
        for (int gg = 0; gg < G; ++gg)
            v |= (mask[(size_t)(b0 + gg) * SEQ + i] != 0 ? 1u : 0u) << gg;
        mkb[d] = v;
    }
    if (t < NT) expend_s[t] = __expf(endt[t]);

    // E^T MFMA A-fragments (row m = 16w+g, k = 32s+8q+e) -- R7-verified layout
    const int m = 16 * w + g;
    bf16x8 ea[3];
#pragma unroll
    for (int s = 0; s < 3; ++s)
#pragma unroll
        for (int e = 0; e < 8; ++e)
            ea[s][e] = f2bf(__expf(trans[(32 * s + 8 * q + e) * NT + m]));

    const float* emg = logits + (size_t)(b0 + g) * SEQ * NT;
    const int jbase = 16 * w + 4 * q;

    // init state at position i0
    s4v prev;
    if (sid == 0) {
#pragma unroll
        for (int r = 0; r < 4; ++r)
            prev[r] = f2bf(__expf(startt[jbase + r] + emg[jbase + r]));
    } else {
#pragma unroll
        for (int r = 0; r < 4; ++r) prev[r] = (short)0x3F80;   // 1.0
    }
    *(s4v*)&AT[0][g][jbase] = prev;

    int K = 0, kcur = 0;
    if (t < G) {
        if (sid == 0) {
            const float ref = __expf(startt[0] + logits[(size_t)(b0 + t) * SEQ * NT]);
            kcur = (int)((__float_as_uint(ref) >> 23) & 0xFFu) - 127;
        }
        sclf[0][t] = __uint_as_float((unsigned)(127 - kcur) << 23);  // 2^-kcur
    }

    float4 emq0 = *(const float4*)&emg[(size_t)(i0 + 1) * NT + jbase];
    float4 emq1 = *(const float4*)&emg[(size_t)(i0 + 2) * NT + jbase];
    __syncthreads();

#define CRF_STEP(i) do {                                                      \
    const int d_ = (i) - i0;                                                  \
    const int rb_ = (d_ - 1) & 1, wb_ = d_ & 1;                               \
    const bf16x8 Bf0 = *(const bf16x8*)&AT[rb_][g][ 0 + 8 * q];               \
    const bf16x8 Bf1 = *(const bf16x8*)&AT[rb_][g][32 + 8 * q];               \
    const bf16x8 Bf2 = *(const bf16x8*)&AT[rb_][g][64 + 8 * q];               \
    const int ip_ = ((i) + 2 <= i1) ? (i) + 2 : i1;                           \
    const float4 emn = *(const float4*)&emg[(size_t)ip_ * NT + jbase];        \
    const float sc = sclf[rb_][g];                                            \
    const unsigned mk = (mkb[d_] >> g) & 1u;                                  \
    const float ws0 = __expf(emq0.x) * sc, ws1 = __expf(emq0.y) * sc;         \
    const float ws2 = __expf(emq0.z) * sc, ws3 = __expf(emq0.w) * sc;         \
    f32x4 acc = {0.f, 0.f, 0.f, 0.f};                                         \
    acc = __builtin_amdgcn_mfma_f32_16x16x32_bf16(ea[0], Bf0, acc, 0, 0, 0);  \
    acc = __builtin_amdgcn_mfma_f32_16x16x32_bf16(ea[1], Bf1, acc, 0, 0, 0);  \
    acc = __builtin_amdgcn_mfma_f32_16x16x32_bf16(ea[2], Bf2, acc, 0, 0, 0);  \
    s4v nw;                                                                   \
    nw[0] = f2bf(acc[0] * ws0); nw[1] = f2bf(acc[1] * ws1);                   \
    nw[2] = f2bf(acc[2] * ws2); nw[3] = f2bf(acc[3] * ws3);                   \
    if (mk) prev = nw;                                                        \
    *(s4v*)&AT[wb_][g][jbase] = prev;                                         \
    if (t < G) {                                                              \
        float scn = sc;                                                       \
        if (mk) {                                                             \
            K += kcur;                                                        \
            kcur = (int)((__float_as_uint(acc[0] * ws0) >> 23) & 0xFFu) - 127;\
            scn = __uint_as_float((unsigned)(127 - kcur) << 23);              \
        }                                                                     \
        sclf[wb_][t] = scn;                                                   \
    }                                                                         \
    emq0 = emq1; emq1 = emn;                                                  \
    asm volatile("s_waitcnt lgkmcnt(0)\n\ts_barrier" ::: "memory");           \
} while (0)

    // warm-up (sid>0): steps i0+1 .. qs, then Lin snapshot
    for (int i = i0 + 1; i <= qs; ++i) CRF_STEP(i);
    if (sid > 0 && t < G) {
        const int pb = (qs - i0) & 1;
        float sd = 0.f;
        for (int j = 0; j < NT; ++j) sd += bf2f(AT[pb][t][j]);
        wsLin[sid * NBAT + b0 + t] = __logf(sd) + (float)K * LN2;
    }
    // main segment: steps qs+1 .. i1 (waves ahead write opposite parity only)
    for (int i = qs + 1; i <= i1; ++i) CRF_STEP(i);
    {
        const int pb = (i1 - i0) & 1;
        if (t < G) {
            float s1 = 0.f, s2 = 0.f;
            for (int j = 0; j < NT; ++j) {
                const float a = bf2f(AT[pb][t][j]);
                s1 += a; s2 += a * expend_s[j];
            }
            wsLout[sid * NBAT + b0 + t] = __logf(s1) + (float)K * LN2;
            if (sid == P - 1) wsLend[b0 + t] = __logf(s2) + (float)K * LN2;
        }
    }

    // ---- numerator partials for steps qs+1..i1: chunk c (0..23), batch gn ----
    const int c = t >> 4;
    const int gn = t & 15;
    const float* emp = logits + (size_t)(b0 + gn) * SEQ * NT;
    const int* tgp = tags + (size_t)(b0 + gn) * SEQ;
    float pn = 0.f;
    for (int i = qs + 1 + c; i <= i1; i += 24) {
        if ((mkb[i - i0] >> gn) & 1u) {
            const int tp = tgp[i - 1], tc = tgp[i];
            pn += trans[tp * NT + tc] + emp[(size_t)i * NT + tc];
        }
    }
    int pc = 0;
    if (sid == P - 1)
        for (int i = c; i < SEQ; i += 24)
            pc += (mask[(size_t)(b0 + gn) * SEQ + i] != 0);
    nred[c][gn] = pn; cred[c][gn] = pc;
    __syncthreads();

    if (t < G) {
        float num = 0.f; int cnt = 0;
        for (int cc = 0; cc < 24; ++cc) { num += nred[cc][t]; cnt += cred[cc][t]; }
        const int* tgq = tags + (size_t)(b0 + t) * SEQ;
        if (sid == 0)
            num += startt[tgq[0]] + logits[(size_t)(b0 + t) * SEQ * NT + tgq[0]];
        if (sid == P - 1)
            num += endt[tgq[cnt - 1]];
        wsNum[sid * NBAT + b0 + t] = num;
    }
}

// telescoping combine: denom_b = Lend_b + sum_{s>=1}(Lout[s-1]-Lin[s]); out = sum llh
__launch_bounds__(NBAT)
__global__ void crf_combine(const float* __restrict__ wsLin,
                            const float* __restrict__ wsLout,
                            const float* __restrict__ wsNum,
                            const float* __restrict__ wsLend,
                            float* __restrict__ out)
{
    const int b = threadIdx.x;    // 512 threads = 8 waves
    float num = 0.f;
#pragma unroll
    for (int s = 0; s < P; ++s) num += wsNum[s * NBAT + b];
    float denom = wsLend[b];
#pragma unroll
    for (int s = 1; s < P; ++s)
        denom += wsLout[(s - 1) * NBAT + b] - wsLin[s * NBAT + b];
    float v = num - denom;
    v += __shfl_xor(v, 1);  v += __shfl_xor(v, 2);  v += __shfl_xor(v, 4);
    v += __shfl_xor(v, 8);  v += __shfl_xor(v, 16); v += __shfl_xor(v, 32);
    __shared__ float r[8];
    if ((b & 63) == 0) r[b >> 6] = v;
    __syncthreads();
    if (b == 0) {
        float s = 0.f;
        for (int i = 0; i < 8; ++i) s += r[i];
        out[0] = s;
    }
}

extern "C" void kernel_launch(void* const* d_in, const int* in_sizes, int n_in,
                              void* d_out, int out_size, void* d_ws, size_t ws_size,
                              hipStream_t stream)
{
    const float* logits = (const float*)d_in[0];
    const int*   tags   = (const int*)  d_in[1];
    const int*   mask   = (const int*)  d_in[2];
    const float* trans  = (const float*)d_in[3];
    const float* startt = (const float*)d_in[4];
    const float* endt   = (const float*)d_in[5];

    float* wsf = (float*)d_ws;
    float* wsLin  = wsf;
    float* wsLout = wsf + P * NBAT;
    float* wsNum  = wsf + 2 * P * NBAT;
    float* wsLend = wsf + 3 * P * NBAT;

    crf_seg<<<(NBAT / G) * P, TPB, 0, stream>>>(logits, tags, mask, trans,
                                                startt, endt,
                                                wsLin, wsLout, wsNum, wsLend);
    crf_combine<<<1, NBAT, 0, stream>>>(wsLin, wsLout, wsNum, wsLend, (float*)d_out);
}